// Round 3
// baseline (107.381 us; speedup 1.0000x reference)
//
#include <hip/hip_runtime.h>

// BSpline evaluation, MI355X.
// t [2048] f32 sorted, c [512,2048] f32, delta [1] i32.
// out = sample_points [S] ++ spline_values [S, DIM]; S=32768, DIM=512.
// R7: CALIBRATION PROBE. Kernel is byte-identical to R6; it is launched
// TWICE (idempotent recompute). Purpose: dur_us delta vs R6 measures the
// kernel's true in-window duration, which rocprof's top-5 (all harness
// poison-fills at ~43.5 us) cannot show. Disambiguates:
//   S1 kernel~43us (dur -> ~130, kernel enters top-5)  -> store-path hunt
//   S2 kernel~13us (dur -> ~102, top-5 unchanged)      -> near roofline
//   dur unchanged (~89)                                -> kernel not timed

#define DEG 3
#define SBLK 128            // samples per block
#define DBLK 128            // dims per block
#define NCOLS 64            // LDS capacity for staged c columns (pow2)
#define CSTRIDE (DBLK + 4)  // 132: rows stay 16B-aligned (528 B), kills 32-way write conflict

typedef float vfloat4 __attribute__((ext_vector_type(4)));

__device__ __forceinline__ float kn(const float* __restrict__ t, int i) {
    return (i < DEG + 1) ? 0.0f : t[i - (DEG + 1)];
}

__global__ __launch_bounds__(256) void bspline_fused(
    const float* __restrict__ t, const float* __restrict__ c,
    const int* __restrict__ delta_p, float* __restrict__ out_pts,
    vfloat4* __restrict__ out_spline, int S, int NK, int DIM, int nd)
{
    __shared__ __attribute__((aligned(16))) float lc[NCOLS][CSTRIDE];
    __shared__ vfloat4 bwS[SBLK];
    __shared__ int jS[SBLK];

    const int tid = threadIdx.x;
    const int dchunk = blockIdx.x % nd;
    const int sb = blockIdx.x / nd;
    const int s0 = sb * SBLK;
    const int dbase = dchunk * DBLK;

    // ---- phase 1: span search + weight triangle (threads 0..SBLK-1) ----
    if (tid < SBLK) {
        const int s = s0 + tid;
        const int sc = (s < S) ? s : (S - 1);
        const float delta = (float)(*delta_p);
        const float sv = (float)sc * delta;
        if (dchunk == 0 && s < S) out_pts[s] = sv;

        // rightmost j in [DEG, NK+DEG-1] with kn(j) <= sv
        int lo = DEG, hi = NK + DEG - 1;
        while (lo < hi) {
            int mid = (lo + hi + 1) >> 1;
            if (kn(t, mid) <= sv) lo = mid; else hi = mid - 1;
        }
        int j = lo;
        vfloat4 b4 = (vfloat4){0.f, 0.f, 0.f, 0.f};
        if (j < NK) {
            // Cox-de Boor triangle: N[d][k] = val(j-d+k, d), where(denom==0 -> 0)
            float N[DEG + 1][DEG + 1];
            N[0][0] = 1.0f;
            #pragma unroll
            for (int d = 1; d <= DEG; ++d) {
                #pragma unroll
                for (int k = 0; k <= d; ++k) {
                    int i = j - d + k;
                    float vpi  = (k >= 1) ? N[d - 1][k - 1] : 0.0f;
                    float vpi1 = (k <= d - 1) ? N[d - 1][k] : 0.0f;
                    float ki   = kn(t, i);
                    float kid  = kn(t, i + d);
                    float ki1  = kn(t, i + 1);
                    float kid1 = kn(t, i + d + 1);
                    float den1 = kid - ki;
                    float den2 = kid1 - ki1;
                    float w1 = (den1 != 0.0f) ? (sv - ki) / den1 : 0.0f;
                    float w2 = (den2 != 0.0f) ? (kid1 - sv) / den2 : 0.0f;
                    N[d][k] = w1 * vpi + w2 * vpi1;
                }
            }
            // stale-column quirk: col i keeps degree min(DEG, NK-1-i)
            float b[DEG + 1];
            #pragma unroll
            for (int m = 0; m <= DEG; ++m) {
                int col = j - DEG + m;
                int deg = NK - 1 - col; if (deg > DEG) deg = DEG;
                int idx = m - DEG + deg;
                b[m] = (idx >= 0) ? N[deg][idx] : 0.0f;
            }
            b4 = (vfloat4){b[0], b[1], b[2], b[3]};
        } else {
            j = NK - 1;   // beyond last span: zero row; clamp for col math
        }
        jS[tid] = j;
        bwS[tid] = b4;
    }
    __syncthreads();

    // ---- phase 2: stage c[dbase..+DBLK) x [colmin..colmax] -> LDS, transposed
    const int colmin = jS[0] - DEG;             // j monotone in s => >= 0
    int nc = jS[SBLK - 1] - colmin + 1;         // actual cols needed
    if (nc > NCOLS) nc = NCOLS;                 // overflow -> fallback path covers
    int ncr = 16, lsh = 4;                      // round up to pow2 (16/32/64)
    while (ncr < nc) { ncr <<= 1; ++lsh; }
    for (int e = tid; e < ncr * DBLK; e += 256) {
        int cc = e & (ncr - 1);                 // consecutive lanes = consecutive cols
        int dd = e >> lsh;
        int col = colmin + cc;
        if (col > NK - 1) col = NK - 1;         // clamped junk never read (b=0 or unused)
        lc[cc][dd] = c[(size_t)(dbase + dd) * NK + col];
    }
    __syncthreads();

    // ---- phase 3: compute + streaming store ----
    const int nv = DIM >> 2;                    // 128
    vfloat4* ob = out_spline + (size_t)s0 * nv + (dbase >> 2);
    #pragma unroll
    for (int k = 0; k < (SBLK * (DBLK >> 2)) / 256; ++k) {   // 16 iters
        const int it = k * 256 + tid;
        const int sl = it >> 5;                 // sample within block (32 float4/row-chunk)
        const int d4 = it & 31;                 // float4 index within dim chunk
        const int j = jS[sl];                   // broadcast LDS reads (32 lanes same addr)
        const vfloat4 b = bwS[sl];
        const int cl = j - DEG - colmin;        // local col of first tap
        vfloat4 r;
        if (cl + DEG < NCOLS) {                 // uniform; ~always true
            const float* p = &lc[cl][d4 << 2];
            vfloat4 a0 = *(const vfloat4*)(p);
            vfloat4 a1 = *(const vfloat4*)(p + CSTRIDE);
            vfloat4 a2 = *(const vfloat4*)(p + 2 * CSTRIDE);
            vfloat4 a3 = *(const vfloat4*)(p + 3 * CSTRIDE);
            r = b.x * a0 + b.y * a1 + b.z * a2 + b.w * a3;
        } else {                                // guaranteed-correct rare fallback
            float rv[4];
            #pragma unroll
            for (int q = 0; q < 4; ++q) {
                const float* cq = c + (size_t)(dbase + (d4 << 2) + q) * NK + (j - DEG);
                rv[q] = b.x * cq[0] + b.y * cq[1] + b.z * cq[2] + b.w * cq[3];
            }
            r = (vfloat4){rv[0], rv[1], rv[2], rv[3]};
        }
        if (s0 + sl < S)
            ob[(size_t)sl * nv + d4] = r;
    }
}

extern "C" void kernel_launch(void* const* d_in, const int* in_sizes, int n_in,
                              void* d_out, int out_size, void* d_ws, size_t ws_size,
                              hipStream_t stream) {
    const float* t = (const float*)d_in[0];
    const float* c = (const float*)d_in[1];
    const int* delta = (const int*)d_in[2];
    const int NK = in_sizes[0];                 // 2048
    const int DIM = in_sizes[1] / NK;           // 512
    const int S = out_size / (1 + DIM);         // 32768

    const int nd = DIM / DBLK;                  // 4
    const int nsb = (S + SBLK - 1) / SBLK;      // 256

    // CALIBRATION: two identical, idempotent launches. dur_us(R7) - dur_us(R6)
    // = one kernel's true in-window duration.
    bspline_fused<<<nsb * nd, 256, 0, stream>>>(
        t, c, delta, (float*)d_out,
        (vfloat4*)((float*)d_out + S), S, NK, DIM, nd);
    bspline_fused<<<nsb * nd, 256, 0, stream>>>(
        t, c, delta, (float*)d_out,
        (vfloat4*)((float*)d_out + S), S, NK, DIM, nd);
}

// Round 4
// 88.187 us; speedup vs baseline: 1.2176x; 1.2176x over previous
//
#include <hip/hip_runtime.h>

// BSpline evaluation, MI355X.
// t [2048] f32 sorted, c [512,2048] f32, delta [1] i32.
// out = sample_points [S] ++ spline_values [S, DIM]; S=32768, DIM=512.
// R8: calibration (R7) showed kernel = 18.4 us vs ~13.5 us pipe floor
// (67 MB stores @6.2 TB/s + ~20 MB fetch + 270 MB LDS). Restructure for
// store contiguity + finer phase grain + XCD L2 locality:
//   SBLK 64, DBLK 256: each wave stores 1024 B contiguous (was 2x512B),
//   each wave LDS-reads 1024 B sequential (conflict-free), phases are
//   half as long (better cross-block overlap at 4 blocks/CU),
//   bijective XCD-chunk swizzle keeps each XCD's c window (~1 MB) in L2.

#define DEG 3
#define SBLK 64             // samples per block
#define DBLK 256            // dims per block
#define NCOLS 32            // LDS capacity for staged c columns (pow2)
#define CSTRIDE (DBLK + 4)  // 260: rows stay 16B-aligned, break pow2 stride

typedef float vfloat4 __attribute__((ext_vector_type(4)));

__device__ __forceinline__ float kn(const float* __restrict__ t, int i) {
    return (i < DEG + 1) ? 0.0f : t[i - (DEG + 1)];
}

__global__ __launch_bounds__(256) void bspline_fused(
    const float* __restrict__ t, const float* __restrict__ c,
    const int* __restrict__ delta_p, float* __restrict__ out_pts,
    vfloat4* __restrict__ out_spline, int S, int NK, int DIM, int nd, int nwg)
{
    __shared__ __attribute__((aligned(16))) float lc[NCOLS][CSTRIDE];
    __shared__ vfloat4 bwS[SBLK];
    __shared__ int jS[SBLK];

    const int tid = threadIdx.x;
    // bijective XCD-chunk swizzle (nwg % 8 == 0): round-robin dispatch puts
    // bid%8 on XCD bid%8; give each XCD a CONTIGUOUS logical range so its
    // c-window stays L2-resident and its sample range is contiguous.
    const int bid = blockIdx.x;
    const int L = (bid & 7) * (nwg >> 3) + (bid >> 3);
    const int dchunk = L & (nd - 1);
    const int sb = L >> 1;                      // nd == 2
    const int s0 = sb * SBLK;
    const int dbase = dchunk * DBLK;

    // ---- phase 1: span search + weight triangle (threads 0..SBLK-1) ----
    if (tid < SBLK) {
        const int s = s0 + tid;
        const int sc = (s < S) ? s : (S - 1);
        const float delta = (float)(*delta_p);
        const float sv = (float)sc * delta;
        if (dchunk == 0 && s < S) out_pts[s] = sv;

        // rightmost j in [DEG, NK+DEG-1] with kn(j) <= sv
        int lo = DEG, hi = NK + DEG - 1;
        while (lo < hi) {
            int mid = (lo + hi + 1) >> 1;
            if (kn(t, mid) <= sv) lo = mid; else hi = mid - 1;
        }
        int j = lo;
        vfloat4 b4 = (vfloat4){0.f, 0.f, 0.f, 0.f};
        if (j < NK) {
            // Cox-de Boor triangle: N[d][k] = val(j-d+k, d), where(denom==0 -> 0)
            float N[DEG + 1][DEG + 1];
            N[0][0] = 1.0f;
            #pragma unroll
            for (int d = 1; d <= DEG; ++d) {
                #pragma unroll
                for (int k = 0; k <= d; ++k) {
                    int i = j - d + k;
                    float vpi  = (k >= 1) ? N[d - 1][k - 1] : 0.0f;
                    float vpi1 = (k <= d - 1) ? N[d - 1][k] : 0.0f;
                    float ki   = kn(t, i);
                    float kid  = kn(t, i + d);
                    float ki1  = kn(t, i + 1);
                    float kid1 = kn(t, i + d + 1);
                    float den1 = kid - ki;
                    float den2 = kid1 - ki1;
                    float w1 = (den1 != 0.0f) ? (sv - ki) / den1 : 0.0f;
                    float w2 = (den2 != 0.0f) ? (kid1 - sv) / den2 : 0.0f;
                    N[d][k] = w1 * vpi + w2 * vpi1;
                }
            }
            // stale-column quirk: col i keeps degree min(DEG, NK-1-i)
            float b[DEG + 1];
            #pragma unroll
            for (int m = 0; m <= DEG; ++m) {
                int col = j - DEG + m;
                int deg = NK - 1 - col; if (deg > DEG) deg = DEG;
                int idx = m - DEG + deg;
                b[m] = (idx >= 0) ? N[deg][idx] : 0.0f;
            }
            b4 = (vfloat4){b[0], b[1], b[2], b[3]};
        } else {
            j = NK - 1;   // beyond last span: zero row; clamp for col math
        }
        jS[tid] = j;
        bwS[tid] = b4;
    }
    __syncthreads();

    // ---- phase 2: stage c[dbase..+DBLK) x [colmin..colmax] -> LDS, transposed
    const int colmin = jS[0] - DEG;             // j monotone in s => >= 0
    int nc = jS[SBLK - 1] - colmin + 1;         // actual cols needed
    if (nc > NCOLS) nc = NCOLS;                 // overflow -> fallback path covers
    int ncr = 8, lsh = 3;                       // round up to pow2 (8/16/32)
    while (ncr < nc) { ncr <<= 1; ++lsh; }
    for (int e = tid; e < ncr * DBLK; e += 256) {
        int cc = e & (ncr - 1);                 // consecutive lanes = consecutive cols
        int dd = e >> lsh;
        int col = colmin + cc;
        if (col > NK - 1) col = NK - 1;         // clamped junk never read (b=0 or unused)
        lc[cc][dd] = c[(size_t)(dbase + dd) * NK + col];
    }
    __syncthreads();

    // ---- phase 3: compute + streaming store (1 KB contiguous per wave) ----
    const int nv = DIM >> 2;                    // 128
    vfloat4* ob = out_spline + (size_t)s0 * nv + (dbase >> 2);
    #pragma unroll
    for (int k = 0; k < (SBLK * (DBLK >> 2)) / 256; ++k) {   // 16 iters
        const int it = k * 256 + tid;
        const int sl = it >> 6;                 // sample within block (64 float4/row-chunk)
        const int d4 = it & 63;                 // float4 index within dim chunk
        const int j = jS[sl];                   // broadcast LDS reads (wave-uniform sl)
        const vfloat4 b = bwS[sl];
        const int cl = j - DEG - colmin;        // local col of first tap
        vfloat4 r;
        if (cl + DEG < NCOLS) {                 // uniform; ~always true
            const float* p = &lc[cl][d4 << 2];
            vfloat4 a0 = *(const vfloat4*)(p);
            vfloat4 a1 = *(const vfloat4*)(p + CSTRIDE);
            vfloat4 a2 = *(const vfloat4*)(p + 2 * CSTRIDE);
            vfloat4 a3 = *(const vfloat4*)(p + 3 * CSTRIDE);
            r = b.x * a0 + b.y * a1 + b.z * a2 + b.w * a3;
        } else {                                // guaranteed-correct rare fallback
            float rv[4];
            #pragma unroll
            for (int q = 0; q < 4; ++q) {
                const float* cq = c + (size_t)(dbase + (d4 << 2) + q) * NK + (j - DEG);
                rv[q] = b.x * cq[0] + b.y * cq[1] + b.z * cq[2] + b.w * cq[3];
            }
            r = (vfloat4){rv[0], rv[1], rv[2], rv[3]};
        }
        if (s0 + sl < S)
            ob[(size_t)sl * nv + d4] = r;
    }
}

extern "C" void kernel_launch(void* const* d_in, const int* in_sizes, int n_in,
                              void* d_out, int out_size, void* d_ws, size_t ws_size,
                              hipStream_t stream) {
    const float* t = (const float*)d_in[0];
    const float* c = (const float*)d_in[1];
    const int* delta = (const int*)d_in[2];
    const int NK = in_sizes[0];                 // 2048
    const int DIM = in_sizes[1] / NK;           // 512
    const int S = out_size / (1 + DIM);         // 32768

    const int nd = DIM / DBLK;                  // 2
    const int nsb = (S + SBLK - 1) / SBLK;      // 512
    const int nwg = nsb * nd;                   // 1024 (divisible by 8)
    bspline_fused<<<nwg, 256, 0, stream>>>(
        t, c, delta, (float*)d_out,
        (vfloat4*)((float*)d_out + S), S, NK, DIM, nd, nwg);
}

// Round 5
// 88.046 us; speedup vs baseline: 1.2196x; 1.0016x over previous
//
#include <hip/hip_runtime.h>

// BSpline evaluation, MI355X.
// t [2048] f32 sorted, c [512,2048] f32, delta [1] i32.
// out = sample_points [S] ++ spline_values [S, DIM]; S=32768, DIM=512.
// R9: kill single-generation phase serialization (R7 calibration: kernel
// 18.4 us vs ~11-13 us store floor; grid was exactly-resident so phase1/2
// bubbles were chip-wide). Changes vs R8:
//  - ONE wave-uniform binary search per block (was 64 divergent), then
//    per-sample linear advance (j monotone, ~4 knots per 64 samples).
//  - c-window stage loads issued IMMEDIATELY after the uniform search
//    (float4 x4 per thread -> regs); latency hides under the weight
//    triangle. One barrier total (was two).
//  - fixed 16-col 4-aligned stage window (typ. need ~7-10; exact global
//    fallback for the ~0.1% rows exceeding it).
//  - LDS 34.6 -> ~18 KB => 8 blocks/CU (32 waves), 2x wave count.

#define DEG 3
#define SBLK 64             // samples per block
#define DBLK 256            // dims per block
#define NSTAGE 16           // staged col window (4-aligned base)
#define CSTRIDE (DBLK + 4)  // 260: 16B-aligned rows, non-pow2 stride

typedef float vfloat4 __attribute__((ext_vector_type(4)));

__device__ __forceinline__ float kn(const float* __restrict__ t, int i) {
    return (i < DEG + 1) ? 0.0f : t[i - (DEG + 1)];
}

__global__ __launch_bounds__(256) void bspline_fused(
    const float* __restrict__ t, const float* __restrict__ c,
    const int* __restrict__ delta_p, float* __restrict__ out_pts,
    vfloat4* __restrict__ out_spline, int S, int NK, int DIM, int nd, int nwg)
{
    __shared__ __attribute__((aligned(16))) float lc[NSTAGE][CSTRIDE];
    __shared__ vfloat4 bwS[SBLK];
    __shared__ int jS[SBLK];

    const int tid = threadIdx.x;
    // bijective XCD-chunk swizzle (nwg % 8 == 0): contiguous logical range
    // per XCD -> c-window L2 locality + overlapping windows between
    // sample-neighbor blocks on the same XCD.
    const int bid = blockIdx.x;
    const int L = (bid & 7) * (nwg >> 3) + (bid >> 3);
    const int dchunk = L % nd;
    const int sb = L / nd;
    const int s0 = sb * SBLK;
    const int dbase = dchunk * DBLK;

    const float delta = (float)(*delta_p);

    // ---- wave-uniform span search for the block's first sample ----
    const float sv0 = (float)s0 * delta;
    int lo = DEG, hi = NK + DEG - 1;
    while (lo < hi) {
        int mid = (lo + hi + 1) >> 1;
        if (kn(t, mid) <= sv0) lo = mid; else hi = mid - 1;
    }
    const int j0 = lo;

    int cmin4 = (j0 - DEG) & ~3;                // 4-aligned window base, >= 0
    if (cmin4 > NK - NSTAGE) cmin4 = NK - NSTAGE;

    // ---- issue stage loads NOW; latency overlaps the triangle below ----
    const int c4 = tid & 3;                     // which float4 of the window
    const int dd0 = tid >> 2;                   // dim row within chunk
    vfloat4 st[4];
    #pragma unroll
    for (int i = 0; i < 4; ++i) {
        const int dd = dd0 + 64 * i;
        st[i] = *(const vfloat4*)(c + (size_t)(dbase + dd) * NK + cmin4 + 4 * c4);
    }

    // ---- per-sample span (linear advance) + weight triangle (wave 0) ----
    if (tid < SBLK) {
        const int s = s0 + tid;
        const int sc = (s < S) ? s : (S - 1);
        const float sv = (float)sc * delta;
        if (dchunk == 0 && s < S) out_pts[s] = sv;

        int j = j0;                             // j monotone in s
        while (j < NK + DEG - 1 && kn(t, j + 1) <= sv) ++j;

        vfloat4 b4 = (vfloat4){0.f, 0.f, 0.f, 0.f};
        if (j < NK) {
            // Cox-de Boor triangle: N[d][k] = val(j-d+k, d), where(denom==0 -> 0)
            float N[DEG + 1][DEG + 1];
            N[0][0] = 1.0f;
            #pragma unroll
            for (int d = 1; d <= DEG; ++d) {
                #pragma unroll
                for (int k = 0; k <= d; ++k) {
                    int i = j - d + k;
                    float vpi  = (k >= 1) ? N[d - 1][k - 1] : 0.0f;
                    float vpi1 = (k <= d - 1) ? N[d - 1][k] : 0.0f;
                    float ki   = kn(t, i);
                    float kid  = kn(t, i + d);
                    float ki1  = kn(t, i + 1);
                    float kid1 = kn(t, i + d + 1);
                    float den1 = kid - ki;
                    float den2 = kid1 - ki1;
                    float w1 = (den1 != 0.0f) ? (sv - ki) / den1 : 0.0f;
                    float w2 = (den2 != 0.0f) ? (kid1 - sv) / den2 : 0.0f;
                    N[d][k] = w1 * vpi + w2 * vpi1;
                }
            }
            // stale-column quirk: col i keeps degree min(DEG, NK-1-i)
            float b[DEG + 1];
            #pragma unroll
            for (int m = 0; m <= DEG; ++m) {
                int col = j - DEG + m;
                int deg = NK - 1 - col; if (deg > DEG) deg = DEG;
                int idx = m - DEG + deg;
                b[m] = (idx >= 0) ? N[deg][idx] : 0.0f;
            }
            b4 = (vfloat4){b[0], b[1], b[2], b[3]};
        } else {
            j = NK - 1;   // beyond last span: zero row; clamp for col math
        }
        jS[tid] = j;
        bwS[tid] = b4;
    }

    // ---- write staged regs -> LDS (transposed), single barrier ----
    #pragma unroll
    for (int i = 0; i < 4; ++i) {
        const int dd = dd0 + 64 * i;
        #pragma unroll
        for (int q = 0; q < 4; ++q)
            lc[4 * c4 + q][dd] = st[i][q];
    }
    __syncthreads();

    // ---- compute + streaming store (1 KB contiguous per wave) ----
    const int nv = DIM >> 2;                    // 128
    vfloat4* ob = out_spline + (size_t)s0 * nv + (dbase >> 2);
    #pragma unroll
    for (int k = 0; k < (SBLK * (DBLK >> 2)) / 256; ++k) {   // 16 iters
        const int it = k * 256 + tid;
        const int sl = it >> 6;                 // sample within block (wave-uniform)
        const int d4 = it & 63;                 // float4 index within dim chunk
        const int j = jS[sl];
        const vfloat4 b = bwS[sl];
        const int cl = j - DEG - cmin4;         // local col of first tap
        vfloat4 r;
        if (cl + DEG < NSTAGE) {                // uniform; ~always true
            const float* p = &lc[cl][d4 << 2];
            vfloat4 a0 = *(const vfloat4*)(p);
            vfloat4 a1 = *(const vfloat4*)(p + CSTRIDE);
            vfloat4 a2 = *(const vfloat4*)(p + 2 * CSTRIDE);
            vfloat4 a3 = *(const vfloat4*)(p + 3 * CSTRIDE);
            r = b.x * a0 + b.y * a1 + b.z * a2 + b.w * a3;
        } else {                                // guaranteed-correct rare fallback
            float rv[4];
            #pragma unroll
            for (int q = 0; q < 4; ++q) {
                const float* cq = c + (size_t)(dbase + (d4 << 2) + q) * NK + (j - DEG);
                rv[q] = b.x * cq[0] + b.y * cq[1] + b.z * cq[2] + b.w * cq[3];
            }
            r = (vfloat4){rv[0], rv[1], rv[2], rv[3]};
        }
        if (s0 + sl < S)
            ob[(size_t)sl * nv + d4] = r;
    }
}

extern "C" void kernel_launch(void* const* d_in, const int* in_sizes, int n_in,
                              void* d_out, int out_size, void* d_ws, size_t ws_size,
                              hipStream_t stream) {
    const float* t = (const float*)d_in[0];
    const float* c = (const float*)d_in[1];
    const int* delta = (const int*)d_in[2];
    const int NK = in_sizes[0];                 // 2048
    const int DIM = in_sizes[1] / NK;           // 512
    const int S = out_size / (1 + DIM);         // 32768

    const int nd = DIM / DBLK;                  // 2
    const int nsb = (S + SBLK - 1) / SBLK;      // 512
    const int nwg = nsb * nd;                   // 1024 (divisible by 8)
    bspline_fused<<<nwg, 256, 0, stream>>>(
        t, c, delta, (float*)d_out,
        (vfloat4*)((float*)d_out + S), S, NK, DIM, nd, nwg);
}

// Round 6
// 86.866 us; speedup vs baseline: 1.2362x; 1.0136x over previous
//
#include <hip/hip_runtime.h>

// BSpline evaluation, MI355X.
// t [2048] f32 sorted, c [512,2048] f32, delta [1] i32.
// out = sample_points [S] ++ spline_values [S, DIM]; S=32768, DIM=512.
// R10: R9 with the block-prologue search chain cut from 11 dependent
// load-rounds to 2 wave-parallel probe rounds (ballot+clz). The whole
// grid is resident in ONE generation (4 blocks/CU), so the prologue's
// ~1 us dependent-latency chain is a chip-wide bubble ahead of the
// c-window stage loads. Single-variable change vs R9.
//   round 1: 64 lanes probe kn(DEG+lane*32) -> 32-wide bracket
//   round 2: 32 lanes probe bracket exhaustively -> exact rightmost j0
// Identical result to the binary search (kn monotone, ties exact).

#define DEG 3
#define SBLK 64             // samples per block
#define DBLK 256            // dims per block
#define NSTAGE 16           // staged col window (4-aligned base)
#define CSTRIDE (DBLK + 4)  // 260: 16B-aligned rows, non-pow2 stride

typedef float vfloat4 __attribute__((ext_vector_type(4)));

__device__ __forceinline__ float kn(const float* __restrict__ t, int i) {
    return (i < DEG + 1) ? 0.0f : t[i - (DEG + 1)];
}

__global__ __launch_bounds__(256) void bspline_fused(
    const float* __restrict__ t, const float* __restrict__ c,
    const int* __restrict__ delta_p, float* __restrict__ out_pts,
    vfloat4* __restrict__ out_spline, int S, int NK, int DIM, int nd, int nwg)
{
    __shared__ __attribute__((aligned(16))) float lc[NSTAGE][CSTRIDE];
    __shared__ vfloat4 bwS[SBLK];
    __shared__ int jS[SBLK];

    const int tid = threadIdx.x;
    // bijective XCD-chunk swizzle (nwg % 8 == 0): contiguous logical range
    // per XCD -> c-window L2 locality.
    const int bid = blockIdx.x;
    const int L = (bid & 7) * (nwg >> 3) + (bid >> 3);
    const int dchunk = L % nd;
    const int sb = L / nd;
    const int s0 = sb * SBLK;
    const int dbase = dchunk * DBLK;

    const float delta = (float)(*delta_p);

    // ---- 2-round wave-parallel span search for the block's first sample ----
    // target: rightmost j in [DEG, NK+DEG-1] with kn(j) <= sv0
    const float sv0 = (float)s0 * delta;
    const int lane = tid & 63;
    int p1 = DEG + lane * 32;                       // covers DEG..DEG+2016
    bool ok1 = (p1 <= NK + DEG - 1) && (kn(t, p1) <= sv0);
    unsigned long long m1 = __ballot(ok1);          // lane0 always true (kn=0)
    int seg = 63 - __clzll(m1);
    int base = DEG + seg * 32;                      // kn(base)<=sv0, kn(base+32)>sv0/OOB
    int p2 = base + (lane & 31);
    bool ok2 = (p2 <= NK + DEG - 1) && (kn(t, p2) <= sv0);
    unsigned long long m2 = __ballot(ok2) & 0xffffffffull;
    const int j0 = __builtin_amdgcn_readfirstlane(base + (63 - __clzll(m2)));

    int cmin4 = (j0 - DEG) & ~3;                // 4-aligned window base, >= 0
    if (cmin4 > NK - NSTAGE) cmin4 = NK - NSTAGE;

    // ---- issue stage loads NOW; latency overlaps the triangle below ----
    const int c4 = tid & 3;                     // which float4 of the window
    const int dd0 = tid >> 2;                   // dim row within chunk
    vfloat4 st[4];
    #pragma unroll
    for (int i = 0; i < 4; ++i) {
        const int dd = dd0 + 64 * i;
        st[i] = *(const vfloat4*)(c + (size_t)(dbase + dd) * NK + cmin4 + 4 * c4);
    }

    // ---- per-sample span (linear advance) + weight triangle (wave 0) ----
    if (tid < SBLK) {
        const int s = s0 + tid;
        const int sc = (s < S) ? s : (S - 1);
        const float sv = (float)sc * delta;
        if (dchunk == 0 && s < S) out_pts[s] = sv;

        int j = j0;                             // j monotone in s
        while (j < NK + DEG - 1 && kn(t, j + 1) <= sv) ++j;

        vfloat4 b4 = (vfloat4){0.f, 0.f, 0.f, 0.f};
        if (j < NK) {
            // Cox-de Boor triangle: N[d][k] = val(j-d+k, d), where(denom==0 -> 0)
            float N[DEG + 1][DEG + 1];
            N[0][0] = 1.0f;
            #pragma unroll
            for (int d = 1; d <= DEG; ++d) {
                #pragma unroll
                for (int k = 0; k <= d; ++k) {
                    int i = j - d + k;
                    float vpi  = (k >= 1) ? N[d - 1][k - 1] : 0.0f;
                    float vpi1 = (k <= d - 1) ? N[d - 1][k] : 0.0f;
                    float ki   = kn(t, i);
                    float kid  = kn(t, i + d);
                    float ki1  = kn(t, i + 1);
                    float kid1 = kn(t, i + d + 1);
                    float den1 = kid - ki;
                    float den2 = kid1 - ki1;
                    float w1 = (den1 != 0.0f) ? (sv - ki) / den1 : 0.0f;
                    float w2 = (den2 != 0.0f) ? (kid1 - sv) / den2 : 0.0f;
                    N[d][k] = w1 * vpi + w2 * vpi1;
                }
            }
            // stale-column quirk: col i keeps degree min(DEG, NK-1-i)
            float b[DEG + 1];
            #pragma unroll
            for (int m = 0; m <= DEG; ++m) {
                int col = j - DEG + m;
                int deg = NK - 1 - col; if (deg > DEG) deg = DEG;
                int idx = m - DEG + deg;
                b[m] = (idx >= 0) ? N[deg][idx] : 0.0f;
            }
            b4 = (vfloat4){b[0], b[1], b[2], b[3]};
        } else {
            j = NK - 1;   // beyond last span: zero row; clamp for col math
        }
        jS[tid] = j;
        bwS[tid] = b4;
    }

    // ---- write staged regs -> LDS (transposed), single barrier ----
    #pragma unroll
    for (int i = 0; i < 4; ++i) {
        const int dd = dd0 + 64 * i;
        #pragma unroll
        for (int q = 0; q < 4; ++q)
            lc[4 * c4 + q][dd] = st[i][q];
    }
    __syncthreads();

    // ---- compute + streaming store (1 KB contiguous per wave) ----
    const int nv = DIM >> 2;                    // 128
    vfloat4* ob = out_spline + (size_t)s0 * nv + (dbase >> 2);
    #pragma unroll
    for (int k = 0; k < (SBLK * (DBLK >> 2)) / 256; ++k) {   // 16 iters
        const int it = k * 256 + tid;
        const int sl = it >> 6;                 // sample within block (wave-uniform)
        const int d4 = it & 63;                 // float4 index within dim chunk
        const int j = jS[sl];
        const vfloat4 b = bwS[sl];
        const int cl = j - DEG - cmin4;         // local col of first tap
        vfloat4 r;
        if (cl + DEG < NSTAGE) {                // uniform; ~always true
            const float* p = &lc[cl][d4 << 2];
            vfloat4 a0 = *(const vfloat4*)(p);
            vfloat4 a1 = *(const vfloat4*)(p + CSTRIDE);
            vfloat4 a2 = *(const vfloat4*)(p + 2 * CSTRIDE);
            vfloat4 a3 = *(const vfloat4*)(p + 3 * CSTRIDE);
            r = b.x * a0 + b.y * a1 + b.z * a2 + b.w * a3;
        } else {                                // guaranteed-correct rare fallback
            float rv[4];
            #pragma unroll
            for (int q = 0; q < 4; ++q) {
                const float* cq = c + (size_t)(dbase + (d4 << 2) + q) * NK + (j - DEG);
                rv[q] = b.x * cq[0] + b.y * cq[1] + b.z * cq[2] + b.w * cq[3];
            }
            r = (vfloat4){rv[0], rv[1], rv[2], rv[3]};
        }
        if (s0 + sl < S)
            ob[(size_t)sl * nv + d4] = r;
    }
}

extern "C" void kernel_launch(void* const* d_in, const int* in_sizes, int n_in,
                              void* d_out, int out_size, void* d_ws, size_t ws_size,
                              hipStream_t stream) {
    const float* t = (const float*)d_in[0];
    const float* c = (const float*)d_in[1];
    const int* delta = (const int*)d_in[2];
    const int NK = in_sizes[0];                 // 2048
    const int DIM = in_sizes[1] / NK;           // 512
    const int S = out_size / (1 + DIM);         // 32768

    const int nd = DIM / DBLK;                  // 2
    const int nsb = (S + SBLK - 1) / SBLK;      // 512
    const int nwg = nsb * nd;                   // 1024 (divisible by 8)
    bspline_fused<<<nwg, 256, 0, stream>>>(
        t, c, delta, (float*)d_out,
        (vfloat4*)((float*)d_out + S), S, NK, DIM, nd, nwg);
}